// Round 1
// baseline (348.829 us; speedup 1.0000x reference)
//
#include <hip/hip_runtime.h>

// virtual_state_scatter, dim=1 (bank axis), superposition=True
// B=2048, O=128, D=1024, K=8, fp32.
//
// out[b,o,:] = state[b,o,:]                                  if o not selected
//            = (1-p)*state[b,o,:] + p*substate[b,:]          p = probs of LAST k with idx==o
//
// One block per (b,o) row; 256 threads x float4 = 1024 floats = D.
// Index scan is wave-uniform (b uniform per block) -> scalar loads.

#define B_DIM 2048
#define O_DIM 128
#define D_DIM 1024
#define K_DIM 8

__global__ __launch_bounds__(256) void vbuf_scatter_kernel(
    const float* __restrict__ state,
    const float* __restrict__ substate,
    const int*   __restrict__ sel_index,
    const float* __restrict__ sel_probs,
    float* __restrict__ out)
{
    const int row = blockIdx.x;          // 0 .. B*O-1
    const int b   = row >> 7;            // row / O_DIM
    const int o   = row & (O_DIM - 1);   // row % O_DIM

    // Find the LAST k whose index matches this bank (numpy last-write-wins).
    float p = -1.0f;
#pragma unroll
    for (int k = 0; k < K_DIM; ++k) {
        int idx = sel_index[b * K_DIM + k];   // wave-uniform -> s_load
        if (idx == o) p = sel_probs[b * K_DIM + k];
    }

    const size_t row_off = (size_t)row * D_DIM;
    const float4* src = reinterpret_cast<const float4*>(state + row_off);
    float4*       dst = reinterpret_cast<float4*>(out + row_off);
    const int t = threadIdx.x;           // 0..255, one float4 each

    float4 v = src[t];
    if (p >= 0.0f) {
        const float4* sub = reinterpret_cast<const float4*>(substate + (size_t)b * D_DIM);
        float4 u = sub[t];
        const float om = 1.0f - p;
        v.x = om * v.x + p * u.x;
        v.y = om * v.y + p * u.y;
        v.z = om * v.z + p * u.z;
        v.w = om * v.w + p * u.w;
    }
    dst[t] = v;
}

extern "C" void kernel_launch(void* const* d_in, const int* in_sizes, int n_in,
                              void* d_out, int out_size, void* d_ws, size_t ws_size,
                              hipStream_t stream) {
    const float* state     = (const float*)d_in[0];
    const float* substate  = (const float*)d_in[1];
    const int*   sel_index = (const int*)d_in[2];
    const float* sel_probs = (const float*)d_in[3];
    float* out = (float*)d_out;

    dim3 grid(B_DIM * O_DIM);   // 262144 blocks, one per (b, o) row
    dim3 block(256);
    vbuf_scatter_kernel<<<grid, block, 0, stream>>>(state, substate, sel_index, sel_probs, out);
}